// Round 8
// baseline (140.370 us; speedup 1.0000x reference)
//
#include <hip/hip_runtime.h>

#define NROW 4096
#define DIM  1024
#define TEMP_INV 14.285714285714286f /* 1/0.07 */
#define NBINS 2048
#define HSLOTS 2304  /* 2048 bins + 4-word pad per 32: slot(b) = b + ((b>>5)<<2) */

typedef __attribute__((ext_vector_type(8))) short bf16x8;
typedef __attribute__((ext_vector_type(4))) float f32x4;

__device__ __forceinline__ unsigned f2bf_u(float f) {
  unsigned u = __float_as_uint(f);
  return (u + 0x7FFFu + ((u >> 16) & 1u)) >> 16;  // RNE bf16
}

__device__ __forceinline__ float wave_sum_f(float v) {
#pragma unroll
  for (int off = 32; off > 0; off >>= 1) v += __shfl_down(v, off);
  return v;
}

// ---------------- Kernel 1: L2 normalize rows, emit bf16 ----------------
__global__ __launch_bounds__(256) void normalize_k(const float* __restrict__ X,
                                                   unsigned short* __restrict__ FB) {
  __shared__ float warp_s[4];
  const int row = blockIdx.x;
  const int tid = threadIdx.x;
  const float4* x4 = (const float4*)(X + (size_t)row * DIM);
  float4 v = x4[tid];  // 256 threads * 4 = 1024
  float ss = v.x * v.x + v.y * v.y + v.z * v.z + v.w * v.w;
  ss = wave_sum_f(ss);
  if ((tid & 63) == 0) warp_s[tid >> 6] = ss;
  __syncthreads();
  float total = warp_s[0] + warp_s[1] + warp_s[2] + warp_s[3];
  float inv = 1.0f / fmaxf(sqrtf(total), 1e-12f);
  ushort4 o;
  o.x = (unsigned short)f2bf_u(v.x * inv);
  o.y = (unsigned short)f2bf_u(v.y * inv);
  o.z = (unsigned short)f2bf_u(v.z * inv);
  o.w = (unsigned short)f2bf_u(v.w * inv);
  ((ushort4*)(FB + (size_t)row * DIM))[tid] = o;
}

// ---------------- Kernel 2: sim = (FB @ FB^T) * (1/T), f32 out ----------------
// 128x128 tile, BK=64, 4 waves, 16x16x32 bf16 MFMA.
// T3-minimum 2-phase pipeline: double-buffered LDS (2x32KB), next K-tile's
// global_load_lds issued BEFORE this tile's compute, ONE barrier per K-step.
// Safety: iter t stages buf[(t+1)&1], reads buf[t&1] (disjoint); next-iter
// stage into buf[t&1] is issued after the barrier -> cannot land before all
// reads retired; __syncthreads' vmcnt drain guarantees prefetch landed.
// T2 swizzle (verified: SQ_LDS_BANK_CONFLICT = 0 in round 6): linear LDS dest,
// inverse-swizzled global source (16B-unit ^= row&7), swizzled ds_read.
// T1: XCD-aware bijective block swizzle (1024 blocks % 8 == 0).
__device__ __forceinline__ void stage_tile(const unsigned short* __restrict__ gA,
                                           const unsigned short* __restrict__ gB,
                                           unsigned short* lA, unsigned short* lB) {
  __builtin_amdgcn_global_load_lds((const __attribute__((address_space(1))) unsigned int*)gA,
                                   (__attribute__((address_space(3))) unsigned int*)lA, 16, 0, 0);
  __builtin_amdgcn_global_load_lds((const __attribute__((address_space(1))) unsigned int*)gB,
                                   (__attribute__((address_space(3))) unsigned int*)lB, 16, 0, 0);
}

__global__ __launch_bounds__(256) void gemm_sim(const unsigned short* __restrict__ FB,
                                                float* __restrict__ C) {
  __shared__ unsigned short As[2][128 * 64] __attribute__((aligned(16)));  // 2x16 KB
  __shared__ unsigned short Bs[2][128 * 64] __attribute__((aligned(16)));  // 2x16 KB
  const int tid  = threadIdx.x;
  const int wave = tid >> 6;
  const int lane = tid & 63;
  const int wr = wave >> 1;  // wave row 0..1
  const int wc = wave & 1;   // wave col 0..1

  // T1: XCD swizzle over the 1024-block 1D grid (32x32 tiles)
  const int bid = blockIdx.x;
  const int swz = (bid & 7) * 128 + (bid >> 3);
  const int brow = (swz >> 5) * 128;
  const int bcol = (swz & 31) * 128;

  f32x4 acc[4][4];
#pragma unroll
  for (int m = 0; m < 4; ++m)
#pragma unroll
    for (int n = 0; n < 4; ++n) acc[m][n] = (f32x4){0.f, 0.f, 0.f, 0.f};

  // Staging geometry (256 thr): instr i covers rows i*32 + wave*8 + (lane>>3),
  // 16B-unit (lane&7) with inverse swizzle ^(row&7); LDS dest linear.
  const int s_rl = wave * 8 + (lane >> 3);               // + i*32
  const int s_cs = (((lane & 7) ^ (lane >> 3)) << 3);    // shorts
  const int s_lo = (wave * 8) * 64;                      // wave-uniform LDS base (+i*32*64)
  // ds_read swizzle precompute
  const int fr  = lane & 15;
  const int fk2 = (lane >> 4) << 4;       // byte offset of k-fragment: 0/16/32/48
  const int frx = (fr & 7) << 4;

  const unsigned short* gArow = FB + (size_t)(brow + s_rl) * DIM + s_cs;
  const unsigned short* gBrow = FB + (size_t)(bcol + s_rl) * DIM + s_cs;

  // prologue: stage K-tile 0 into buf 0
#pragma unroll
  for (int i = 0; i < 4; ++i)
    stage_tile(gArow + (size_t)(i * 32) * DIM, gBrow + (size_t)(i * 32) * DIM,
               &As[0][i * 32 * 64 + s_lo], &Bs[0][i * 32 * 64 + s_lo]);
  __syncthreads();

  for (int t = 0; t < 15; ++t) {
    // issue next tile's stage FIRST (targets the other buffer)
    const int nb = (t + 1) & 1;
    const int k0n = (t + 1) * 64;
#pragma unroll
    for (int i = 0; i < 4; ++i)
      stage_tile(gArow + (size_t)(i * 32) * DIM + k0n, gBrow + (size_t)(i * 32) * DIM + k0n,
                 &As[nb][i * 32 * 64 + s_lo], &Bs[nb][i * 32 * 64 + s_lo]);

    // compute current tile
    const unsigned short* Ab = As[t & 1];
    const unsigned short* Bb = Bs[t & 1];
#pragma unroll
    for (int h = 0; h < 2; ++h) {
      const int cb = ((fk2 + h * 64) ^ frx) >> 1;  // swizzled col (shorts)
      bf16x8 af[4], bg[4];
#pragma unroll
      for (int m = 0; m < 4; ++m)
        af[m] = *(const bf16x8*)&Ab[(wr * 64 + m * 16 + fr) * 64 + cb];
#pragma unroll
      for (int n = 0; n < 4; ++n)
        bg[n] = *(const bf16x8*)&Bb[(wc * 64 + n * 16 + fr) * 64 + cb];
#pragma unroll
      for (int m = 0; m < 4; ++m)
#pragma unroll
        for (int n = 0; n < 4; ++n)
          acc[m][n] = __builtin_amdgcn_mfma_f32_16x16x32_bf16(af[m], bg[n], acc[m][n], 0, 0, 0);
    }
    __syncthreads();  // drains vmcnt (prefetch landed) + all buf reads retired
  }

  // last tile (t=15, buf 1), no stage
  {
    const unsigned short* Ab = As[1];
    const unsigned short* Bb = Bs[1];
#pragma unroll
    for (int h = 0; h < 2; ++h) {
      const int cb = ((fk2 + h * 64) ^ frx) >> 1;
      bf16x8 af[4], bg[4];
#pragma unroll
      for (int m = 0; m < 4; ++m)
        af[m] = *(const bf16x8*)&Ab[(wr * 64 + m * 16 + fr) * 64 + cb];
#pragma unroll
      for (int n = 0; n < 4; ++n)
        bg[n] = *(const bf16x8*)&Bb[(wc * 64 + n * 16 + fr) * 64 + cb];
#pragma unroll
      for (int m = 0; m < 4; ++m)
#pragma unroll
        for (int n = 0; n < 4; ++n)
          acc[m][n] = __builtin_amdgcn_mfma_f32_16x16x32_bf16(af[m], bg[n], acc[m][n], 0, 0, 0);
    }
  }

  const int rsub = (lane >> 4) * 4;
#pragma unroll
  for (int m = 0; m < 4; ++m)
#pragma unroll
    for (int n = 0; n < 4; ++n) {
      const int r0 = brow + wr * 64 + m * 16 + rsub;
      const int c  = bcol + wc * 64 + n * 16 + fr;
#pragma unroll
      for (int i = 0; i < 4; ++i)
        C[(size_t)(r0 + i) * NROW + c] = acc[m][n][i] * TEMP_INV;
    }
}

// ---------------- Kernel 3: per-row hard mining + loss ----------------
// One WAVE per row, zero __syncthreads. VGPR-lean (row streamed from L2/L3,
// not register-resident). Single fixed-range histogram select (|sim| < 16,
// 2048 bins). Unchanged from round 6.
__global__ __launch_bounds__(256) void row_loss_k(const float* __restrict__ S,
                                                  const int* __restrict__ labels,
                                                  float* __restrict__ row_out) {
  __shared__ unsigned hist[4][HSLOTS] __attribute__((aligned(16)));  // 36.9 KB
  const int wave = threadIdx.x >> 6;
  const int lane = threadIdx.x & 63;
  const int row  = blockIdx.x * 4 + wave;
  const int my   = labels[row];
  unsigned* H = hist[wave];

  const float4* rp = (const float4*)(S + (size_t)row * NROW);
  const int4*   lp = (const int4*)labels;

  // zero histogram: 2304 words / 64 lanes = 9 x uint4 per lane
#pragma unroll
  for (int z = 0; z < 9; ++z)
    *(uint4*)&H[z * 256 + lane * 4] = (uint4){0u, 0u, 0u, 0u};

  // masks (labels only; element (e,c) is column j = e*256 + lane*4 + c)
  unsigned long long negm = 0ull, posm = 0ull;
#pragma unroll
  for (int e = 0; e < 16; ++e) {
    int4 lb = lp[e * 64 + lane];
    const int j0 = e * 256 + lane * 4;
    if (lb.x != my) negm |= 1ull << (e * 4 + 0); else if (j0 + 0 != row) posm |= 1ull << (e * 4 + 0);
    if (lb.y != my) negm |= 1ull << (e * 4 + 1); else if (j0 + 1 != row) posm |= 1ull << (e * 4 + 1);
    if (lb.z != my) negm |= 1ull << (e * 4 + 2); else if (j0 + 2 != row) posm |= 1ull << (e * 4 + 2);
    if (lb.w != my) negm |= 1ull << (e * 4 + 3); else if (j0 + 3 != row) posm |= 1ull << (e * 4 + 3);
  }

  int nneg = __popcll(negm);
#pragma unroll
  for (int off = 32; off > 0; off >>= 1) nneg += __shfl_xor(nneg, off);
  int k = nneg >> 1;            // floor(count*0.5)
  if (k < 1) k = 1;

  asm volatile("s_waitcnt lgkmcnt(0)" ::: "memory");  // zeros visible wave-wide

  // histogram fill pass (row streamed, not kept)
#pragma unroll 4
  for (int e = 0; e < 16; ++e) {
    float4 v4 = rp[e * 64 + lane];
#pragma unroll
    for (int c = 0; c < 4; ++c) {
      const int idx = e * 4 + c;
      if ((negm >> idx) & 1ull) {
        float v = ((const float*)&v4)[c];
        int b = (int)((v + 16.0f) * 64.0f);
        b = min(max(b, 0), NBINS - 1);
        atomicAdd(&H[b + ((b >> 5) << 2)], 1u);
      }
    }
  }
  asm volatile("s_waitcnt lgkmcnt(0)" ::: "memory");  // counts visible wave-wide

  // suffix scan: lane owns bins [lane*32, lane*32+32) at slots lane*36 + 0..31
  int ts = 0;
#pragma unroll
  for (int z = 0; z < 8; ++z) {
    uint4 h = *(const uint4*)&H[lane * 36 + z * 4];
    ts += (int)(h.x + h.y + h.z + h.w);
  }
  int sfx = ts;
#pragma unroll
  for (int off = 1; off < 64; off <<= 1) {
    int t = __shfl_down(sfx, off);
    sfx += (lane + off < 64) ? t : 0;
  }
  int snext = __shfl_down(sfx, 1);
  if (lane == 63) snext = 0;
  const bool iscross = (sfx >= k) && (snext < k);

  // in-lane descent: find largest bin B with count(bin >= B) >= k
  int B = -1;
  int run = snext;
#pragma unroll
  for (int z = 7; z >= 0; --z) {
    uint4 h = *(const uint4*)&H[lane * 36 + z * 4];
    run += (int)h.w; if (B < 0 && run >= k) B = z * 4 + 3;
    run += (int)h.z; if (B < 0 && run >= k) B = z * 4 + 2;
    run += (int)h.y; if (B < 0 && run >= k) B = z * 4 + 1;
    run += (int)h.x; if (B < 0 && run >= k) B = z * 4 + 0;
  }
  B = iscross ? (lane * 32 + B) : -1;

  unsigned long long mB = __ballot(B >= 0);
  int Bsel = NBINS;  // sentinel: select none (no negatives)
  if (mB != 0ull) {
    int src = __ffsll(mB) - 1;
    Bsel = __shfl(B, src);
  }

  // fused final pass (row streamed again; L2/L3-hot)
  float negexp = 0.f, possum = 0.f, selfv = 0.f;
  int pc = 0;
#pragma unroll 4
  for (int e = 0; e < 16; ++e) {
    float4 v4 = rp[e * 64 + lane];
#pragma unroll
    for (int c = 0; c < 4; ++c) {
      const int idx = e * 4 + c;
      const int j = e * 256 + lane * 4 + c;
      float v = ((const float*)&v4)[c];
      int b = (int)((v + 16.0f) * 64.0f);
      bool sel = ((negm >> idx) & 1ull) && (b >= Bsel);
      negexp += __expf(sel ? v : -1e30f);  // exp(-1e30) -> 0
      if ((posm >> idx) & 1ull) { possum += v; pc++; }
      if (j == row) selfv = v;
    }
  }
#pragma unroll
  for (int off = 32; off > 0; off >>= 1) {
    negexp += __shfl_xor(negexp, off);
    possum += __shfl_xor(possum, off);
    selfv  += __shfl_xor(selfv, off);
    pc     += __shfl_xor(pc, off);
  }
  if (lane == 0) {
    float denom = negexp + expf(selfv) + 1e-10f;
    float logd = logf(denom);
    row_out[row] = (possum - (float)pc * logd) / ((float)pc + 1e-10f);
  }
}

// ---------------- Kernel 4: reduce per-row losses -> scalar ----------------
__global__ __launch_bounds__(256) void final_reduce_k(const float* __restrict__ row_out,
                                                      float* __restrict__ out) {
  __shared__ float ws[4];
  float s = 0.f;
  const float4* rp = (const float4*)row_out;
#pragma unroll
  for (int e = 0; e < 4; ++e) {
    float4 v = rp[e * 256 + threadIdx.x];
    s += v.x + v.y + v.z + v.w;
  }
#pragma unroll
  for (int off = 32; off > 0; off >>= 1) s += __shfl_xor(s, off);
  if ((threadIdx.x & 63) == 0) ws[threadIdx.x >> 6] = s;
  __syncthreads();
  if (threadIdx.x == 0) out[0] = -(ws[0] + ws[1] + ws[2] + ws[3]) * (1.0f / (float)NROW);
}

// ---------------- launcher ----------------
extern "C" void kernel_launch(void* const* d_in, const int* in_sizes, int n_in,
                              void* d_out, int out_size, void* d_ws, size_t ws_size,
                              hipStream_t stream) {
  const float* X    = (const float*)d_in[0];
  const int* labels = (const int*)d_in[1];
  float* out        = (float*)d_out;

  unsigned short* FB = (unsigned short*)d_ws;                       // 8 MB bf16
  float* S = (float*)((char*)d_ws + (size_t)NROW * DIM * 2);        // 64 MB f32
  // per-row losses reuse the FB region (dead after gemm_sim completes)
  float* row_out = (float*)d_ws;

  normalize_k<<<NROW, 256, 0, stream>>>(X, FB);
  gemm_sim<<<1024, 256, 0, stream>>>(FB, S);
  row_loss_k<<<NROW / 4, 256, 0, stream>>>(S, labels, row_out);
  final_reduce_k<<<1, 256, 0, stream>>>(row_out, out);
}